// Round 1
// baseline (187.704 us; speedup 1.0000x reference)
//
#include <hip/hip_runtime.h>
#include <math.h>

#define EMB_D 256

__global__ void ldml_init(float* acc) {
    if (threadIdx.x < 2) acc[threadIdx.x] = 0.0f;
}

__global__ __launch_bounds__(256) void ldml_pairs(
    const float* __restrict__ X,
    const float* __restrict__ bias,
    const int2* __restrict__ pos_idx,
    const int2* __restrict__ neg_idx,
    int P, int wavesPerSide, int pairsPerWave,
    float* __restrict__ acc)
{
    const int lane        = threadIdx.x & 63;
    const int waveInBlock = threadIdx.x >> 6;
    const int wavesInBlk  = blockDim.x >> 6;
    const int waveGlobal  = blockIdx.x * wavesInBlk + waveInBlock;
    const int side        = (waveGlobal >= wavesPerSide) ? 1 : 0;  // 0=pos, 1=neg
    const int w           = waveGlobal - side * wavesPerSide;
    const int2* __restrict__ idx = side ? neg_idx : pos_idx;
    const float b = bias[0];

    int p0 = w * pairsPerWave;
    int p1 = p0 + pairsPerWave;
    if (p1 > P) p1 = P;
    if (p0 > P) p0 = P;

    float waveSum = 0.0f;
    int prev_i = -1;
    float4 a4 = make_float4(0.f, 0.f, 0.f, 0.f);
    const int laneOff = lane << 2;  // 4 floats per lane

    for (int p = p0; p < p1; ++p) {
        int2 ij = idx[p];
        int i = __builtin_amdgcn_readfirstlane(ij.x);
        int j = __builtin_amdgcn_readfirstlane(ij.y);
        if (i != prev_i) {  // wave-uniform branch; pos side reuses row i for 63 pairs
            a4 = *(const float4*)(X + (size_t)i * EMB_D + laneOff);
            prev_i = i;
        }
        float4 b4 = *(const float4*)(X + (size_t)j * EMB_D + laneOff);
        float dx = a4.x - b4.x;
        float dy = a4.y - b4.y;
        float dz = a4.z - b4.z;
        float dw = a4.w - b4.w;
        float d = dx * dx;
        d = fmaf(dy, dy, d);
        d = fmaf(dz, dz, d);
        d = fmaf(dw, dw, d);
        // butterfly reduce across the 64-lane wave
        #pragma unroll
        for (int off = 32; off > 0; off >>= 1)
            d += __shfl_xor(d, off, 64);
        // loss = softplus(z); pos: z = d - b, neg: z = b - d  (TEMP = 1)
        float z  = side ? (b - d) : (d - b);
        float sp = fmaxf(z, 0.0f) + log1pf(expf(-fabsf(z)));
        waveSum += sp;  // uniform across lanes
    }

    // block reduction: one (or two, if a block straddles the side boundary) atomics
    __shared__ float smemSum[8];
    if (lane == 0) smemSum[waveInBlock] = waveSum;
    __syncthreads();
    if (threadIdx.x == 0) {
        float s0 = 0.f, s1 = 0.f;
        for (int k = 0; k < wavesInBlk; ++k) {
            int wg = blockIdx.x * wavesInBlk + k;
            if (wg >= wavesPerSide) s1 += smemSum[k];
            else                    s0 += smemSum[k];
        }
        if (s0 != 0.f) atomicAdd(&acc[0], s0);
        if (s1 != 0.f) atomicAdd(&acc[1], s1);
    }
}

__global__ void ldml_finalize(const float* __restrict__ acc,
                              float* __restrict__ out, float invP) {
    if (threadIdx.x < 2) out[threadIdx.x] = acc[threadIdx.x] * invP;
}

extern "C" void kernel_launch(void* const* d_in, const int* in_sizes, int n_in,
                              void* d_out, int out_size, void* d_ws, size_t ws_size,
                              hipStream_t stream) {
    const float* X        = (const float*)d_in[0];
    const float* bias     = (const float*)d_in[1];
    const int2*  pos_idx  = (const int2*)d_in[2];
    const int2*  neg_idx  = (const int2*)d_in[3];
    const int    P        = in_sizes[2] / 2;   // 258048

    float* acc = (float*)d_ws;   // 2 floats of scratch
    float* out = (float*)d_out;

    const int pairsPerWave = 63;                                  // matches pos run-length
    const int wavesPerSide = (P + pairsPerWave - 1) / pairsPerWave; // 4096
    const int totalWaves   = 2 * wavesPerSide;                     // 8192
    const int blocks       = (totalWaves * 64 + 255) / 256;        // 2048

    hipLaunchKernelGGL(ldml_init, dim3(1), dim3(64), 0, stream, acc);
    hipLaunchKernelGGL(ldml_pairs, dim3(blocks), dim3(256), 0, stream,
                       X, bias, pos_idx, neg_idx, P, wavesPerSide, pairsPerWave, acc);
    hipLaunchKernelGGL(ldml_finalize, dim3(1), dim3(64), 0, stream,
                       acc, out, 1.0f / (float)P);
}

// Round 2
// 122.200 us; speedup vs baseline: 1.5360x; 1.5360x over previous
//
#include <hip/hip_runtime.h>
#include <math.h>

#define EMB_D 256

// One wave processes a batch of 64 pairs:
//  Phase A: for each pair p (wave-uniform rows via readlane), lanes compute a
//           float4 partial of the squared distance, pre-combine across the two
//           32-lane halves (shfl_xor 32), and write 32 partials to LDS
//           (stride 33 -> bank = (p + lane) % 32, conflict-free).
//  Phase B: lane l sums pair l's 32 partials (bank = (l + k) % 32, 2-way free),
//           computes ONE softplus per lane, then a single wave butterfly + one
//           atomic per block. Softplus/reduction amortize 64x vs R1.
__global__ __launch_bounds__(256) void ldml_main(
    const float* __restrict__ X,
    const float* __restrict__ bias,
    const int2* __restrict__ pos_idx,
    const int2* __restrict__ neg_idx,
    int P, int blocksPerSide,
    float* __restrict__ out, float invP)
{
    __shared__ float wbuf[4 * 64 * 33];   // 33.8 KB: per-wave 64 pairs x 32(+1) partials
    __shared__ float bsum[4];

    const int lane = threadIdx.x & 63;
    const int wv   = threadIdx.x >> 6;
    const int side = (blockIdx.x >= blocksPerSide) ? 1 : 0;   // 0=pos, 1=neg
    const int blockInSide = blockIdx.x - side * blocksPerSide;
    const int batch = blockInSide * 4 + wv;                   // wave's 64-pair batch
    const int pairBase = batch * 64;
    const int2* __restrict__ idx = side ? neg_idx : pos_idx;

    int myIdx = pairBase + lane;
    bool valid = myIdx < P;
    int2 myPair = idx[valid ? myIdx : 0];
    int vi = myPair.x, vj = myPair.y;

    float* wb = wbuf + wv * (64 * 33);
    const int laneOff = lane << 2;        // 4 floats / lane -> 1 KB coalesced row

    int prev_i = -1;
    float4 a4 = make_float4(0.f, 0.f, 0.f, 0.f);
    #pragma unroll 8
    for (int p = 0; p < 64; ++p) {
        int i = __builtin_amdgcn_readlane(vi, p);   // wave-uniform -> SGPR
        int j = __builtin_amdgcn_readlane(vj, p);
        if (i != prev_i) {                          // scalar branch; pos side: 63-run reuse
            a4 = *(const float4*)(X + (size_t)i * EMB_D + laneOff);
            prev_i = i;
        }
        float4 b4 = *(const float4*)(X + (size_t)j * EMB_D + laneOff);
        float dx = a4.x - b4.x;
        float dy = a4.y - b4.y;
        float dz = a4.z - b4.z;
        float dw = a4.w - b4.w;
        float d = dx * dx;
        d = fmaf(dy, dy, d);
        d = fmaf(dz, dz, d);
        d = fmaf(dw, dw, d);
        d += __shfl_xor(d, 32, 64);                 // halves combined -> 32 partials
        if (lane < 32) wb[p * 33 + lane] = d;
    }
    __syncthreads();

    // Phase B: lane l owns pair l
    float dist = 0.f;
    #pragma unroll
    for (int k = 0; k < 32; ++k) dist += wb[lane * 33 + k];

    const float b = bias[0];
    float z = side ? (b - dist) : (dist - b);       // TEMP = 1
    float sp = fmaxf(z, 0.f) + log1pf(expf(-fabsf(z)));
    if (!valid) sp = 0.f;

    #pragma unroll
    for (int off = 32; off > 0; off >>= 1)
        sp += __shfl_xor(sp, off, 64);

    if (lane == 0) bsum[wv] = sp;
    __syncthreads();
    if (threadIdx.x == 0) {
        float s = (bsum[0] + bsum[1]) + (bsum[2] + bsum[3]);
        atomicAdd(&out[side], s * invP);            // one atomic per block
    }
}

extern "C" void kernel_launch(void* const* d_in, const int* in_sizes, int n_in,
                              void* d_out, int out_size, void* d_ws, size_t ws_size,
                              hipStream_t stream) {
    const float* X       = (const float*)d_in[0];
    const float* bias    = (const float*)d_in[1];
    const int2*  pos_idx = (const int2*)d_in[2];
    const int2*  neg_idx = (const int2*)d_in[3];
    const int    P       = in_sizes[2] / 2;                 // 258048

    float* out = (float*)d_out;

    // zero the two accumulators; kernel atomically adds scaled partials
    hipMemsetAsync(out, 0, 2 * sizeof(float), stream);

    const int pairsPerBlock = 4 * 64;                        // 4 waves x 64-pair batch
    const int blocksPerSide = (P + pairsPerBlock - 1) / pairsPerBlock;  // 1008
    const int totalBlocks   = 2 * blocksPerSide;             // 2016

    hipLaunchKernelGGL(ldml_main, dim3(totalBlocks), dim3(256), 0, stream,
                       X, bias, pos_idx, neg_idx, P, blocksPerSide,
                       out, 1.0f / (float)P);
}

// Round 3
// 101.372 us; speedup vs baseline: 1.8516x; 1.2055x over previous
//
#include <hip/hip_runtime.h>
#include <math.h>

#define EMB_D 256

// One wave owns 64 pairs. Straight-line phase A (no scalar branch -> compiler
// can software-pipeline many global_load_dwordx4 in flight): per pair, lanes
// hold float4 of each row (coalesced 1 KB), 2-step shfl pre-combine leaves 16
// partials/pair written to LDS at stride 17 (odd -> worst 2-way bank alias,
// free). Phase B: lane l sums pair l's 16 partials, ONE softplus per lane,
// wave butterfly, per-block partial to ws (non-atomic; finalize reduces).
// LDS 17.4 KB/block -> LDS allows 8 blocks/CU (vs 4 at R2's 34 KB).
__global__ __launch_bounds__(256) void ldml_main(
    const float* __restrict__ X,
    const float* __restrict__ bias,
    const int2* __restrict__ pos_idx,
    const int2* __restrict__ neg_idx,
    int P, int blocksPerSide,
    float* __restrict__ blockSums)
{
    __shared__ float wbuf[4 * 64 * 17];   // 17.4 KB
    __shared__ float wsum[4];

    const int lane = threadIdx.x & 63;
    const int wv   = threadIdx.x >> 6;
    const int side = (blockIdx.x >= blocksPerSide) ? 1 : 0;   // 0=pos, 1=neg
    const int blockInSide = blockIdx.x - side * blocksPerSide;
    const int pairBase = (blockInSide * 4 + wv) * 64;
    const int2* __restrict__ idx = side ? neg_idx : pos_idx;

    const int myIdx = pairBase + lane;
    const bool valid = myIdx < P;
    const int2 myPair = idx[valid ? myIdx : 0];
    const int vi = myPair.x, vj = myPair.y;

    float* wb = wbuf + wv * (64 * 17);
    const int laneOff = lane << 2;        // 4 floats / lane -> coalesced 1 KB row

    #pragma unroll 4
    for (int p = 0; p < 64; ++p) {
        const int i = __builtin_amdgcn_readlane(vi, p);   // wave-uniform -> SGPR
        const int j = __builtin_amdgcn_readlane(vj, p);
        const float4 a4 = *(const float4*)(X + ((size_t)(unsigned)i << 8) + laneOff);
        const float4 b4 = *(const float4*)(X + ((size_t)(unsigned)j << 8) + laneOff);
        float dx = a4.x - b4.x;
        float dy = a4.y - b4.y;
        float dz = a4.z - b4.z;
        float dw = a4.w - b4.w;
        float d = dx * dx;
        d = fmaf(dy, dy, d);
        d = fmaf(dz, dz, d);
        d = fmaf(dw, dw, d);
        d += __shfl_xor(d, 32, 64);
        d += __shfl_xor(d, 16, 64);       // 16 partials remain (lanes 0..15)
        if (lane < 16) wb[p * 17 + lane] = d;
    }
    __syncthreads();

    // Phase B: lane l owns pair l; banks (17l+k)%32, 17 coprime 32 -> 2-way max
    float dist = 0.f;
    #pragma unroll
    for (int k = 0; k < 16; ++k) dist += wb[lane * 17 + k];

    const float b = bias[0];
    float z  = side ? (b - dist) : (dist - b);   // TEMP = 1
    float sp = fmaxf(z, 0.f) + log1pf(expf(-fabsf(z)));
    if (!valid) sp = 0.f;

    #pragma unroll
    for (int off = 32; off > 0; off >>= 1)
        sp += __shfl_xor(sp, off, 64);

    if (lane == 0) wsum[wv] = sp;
    __syncthreads();
    if (threadIdx.x == 0)
        blockSums[blockIdx.x] = (wsum[0] + wsum[1]) + (wsum[2] + wsum[3]);
}

__global__ __launch_bounds__(256) void ldml_finalize(
    const float* __restrict__ blockSums, int blocksPerSide,
    float* __restrict__ out, float invP)
{
    float sPos = 0.f, sNeg = 0.f;
    for (int t = threadIdx.x; t < 2 * blocksPerSide; t += 256) {
        float v = blockSums[t];
        if (t < blocksPerSide) sPos += v; else sNeg += v;
    }
    #pragma unroll
    for (int off = 32; off > 0; off >>= 1) {
        sPos += __shfl_xor(sPos, off, 64);
        sNeg += __shfl_xor(sNeg, off, 64);
    }
    __shared__ float sm[8];
    const int lane = threadIdx.x & 63, wv = threadIdx.x >> 6;
    if (lane == 0) { sm[wv * 2] = sPos; sm[wv * 2 + 1] = sNeg; }
    __syncthreads();
    if (threadIdx.x == 0) {
        out[0] = (sm[0] + sm[2] + sm[4] + sm[6]) * invP;
        out[1] = (sm[1] + sm[3] + sm[5] + sm[7]) * invP;
    }
}

extern "C" void kernel_launch(void* const* d_in, const int* in_sizes, int n_in,
                              void* d_out, int out_size, void* d_ws, size_t ws_size,
                              hipStream_t stream) {
    const float* X       = (const float*)d_in[0];
    const float* bias    = (const float*)d_in[1];
    const int2*  pos_idx = (const int2*)d_in[2];
    const int2*  neg_idx = (const int2*)d_in[3];
    const int    P       = in_sizes[2] / 2;                 // 258048

    float* blockSums = (float*)d_ws;                        // 2016 floats scratch
    float* out       = (float*)d_out;

    const int pairsPerBlock = 4 * 64;                       // 4 waves x 64 pairs
    const int blocksPerSide = (P + pairsPerBlock - 1) / pairsPerBlock;  // 1008
    const int totalBlocks   = 2 * blocksPerSide;            // 2016

    hipLaunchKernelGGL(ldml_main, dim3(totalBlocks), dim3(256), 0, stream,
                       X, bias, pos_idx, neg_idx, P, blocksPerSide, blockSums);
    hipLaunchKernelGGL(ldml_finalize, dim3(1), dim3(256), 0, stream,
                       blockSums, blocksPerSide, out, 1.0f / (float)P);
}